// Round 7
// baseline (179.338 us; speedup 1.0000x reference)
//
#include <hip/hip_runtime.h>
#include <cmath>

#define DIM    64
#define MCODE  512
#define ROWS   131072
#define QELEMS 8388608   // 32*4096*64
#define BM     128       // rows per block
#define TPB    256

typedef _Float16 f16x8 __attribute__((ext_vector_type(8)));
typedef float    f32x16 __attribute__((ext_vector_type(16)));

#define COMP(v, c) ((c) == 0 ? (v).x : (c) == 1 ? (v).y : (c) == 2 ? (v).z : (v).w)

// ---------------- prep: cvec, semax, fp16-tiled codebook; zero fallback accumulators
__global__ __launch_bounds__(512) void vq_prep(const float* __restrict__ E,
                                               float* __restrict__ cvec,
                                               float* __restrict__ semaxp,
                                               _Float16* __restrict__ Ebf,
                                               unsigned int* __restrict__ counts,
                                               double* __restrict__ lsum) {
    __shared__ float smax[512];
    const int m = threadIdx.x;            // 512 threads, 1 block
    counts[m] = 0u;
    if (m == 0) *lsum = 0.0;
    const float* e = E + (size_t)m * DIM;
    float r[8];
#pragma unroll
    for (int j = 0; j < 8; ++j) r[j] = e[j] * e[j];
#pragma unroll
    for (int i = 1; i < 8; ++i)
#pragma unroll
        for (int j = 0; j < 8; ++j) r[j] += e[8 * i + j] * e[8 * i + j];
    const float c = ((r[0] + r[1]) + (r[2] + r[3])) + ((r[4] + r[5]) + (r[6] + r[7]));
    cvec[m] = c;
    smax[m] = c;
    __syncthreads();
    for (int s = 256; s > 0; s >>= 1) {
        if (m < s) smax[m] = fmaxf(smax[m], smax[m + s]);
        __syncthreads();
    }
    if (m == 0) *semaxp = sqrtf(smax[0]) * 1.000001f;

    // fp16 codebook, MFMA-A tiled granule order:
    // code m: T=m>>5 (0..15), lrow=m&31; k-granule g (8 halfs each) ->
    // granule index = T*256 + g*32 + lrow
    const int T = m >> 5, lrow = m & 31;
    f16x8* dst = (f16x8*)Ebf;
#pragma unroll
    for (int g = 0; g < 8; ++g) {
        f16x8 hv;
#pragma unroll
        for (int j = 0; j < 8; ++j) hv[j] = (_Float16)e[8 * g + j];
        dst[T * 256 + g * 32 + lrow] = hv;
    }
}

// ---------------- main: f16-MFMA filter (codes=A-rows, x=B-cols) + exact rescue
// No LDS staging: E fragments stream from L2-resident pre-tiled Ebf.
__global__ __launch_bounds__(TPB, 5) void vq_main(const float* __restrict__ X,
                                                  const float* __restrict__ E,
                                                  const float* __restrict__ cvec,
                                                  const float* __restrict__ semaxp,
                                                  const _Float16* __restrict__ Ebf,
                                                  float* __restrict__ out,
                                                  unsigned int* __restrict__ counts,
                                                  double* __restrict__ lsum,
                                                  unsigned int* __restrict__ slab) {
    __shared__ int bidxs[BM];
    __shared__ unsigned int hist[MCODE];   // 2 KB
    __shared__ int rlist[BM];
    __shared__ int rcount;
    __shared__ double red[TPB / 64];

    const int tid = threadIdx.x;
    const int w = tid >> 6;
    const int l = tid & 63;
    const int lhalf = l >> 5;
    const int lrow = l & 31;

    for (int i = tid; i < MCODE; i += TPB) hist[i] = 0u;
    if (tid == 0) rcount = 0;
    __syncthreads();   // hist zero visible before any LDS atomic

    // ---- x fragments straight from global: lane owns row w*32+lrow,
    //      k-granules 4c + 2*lhalf + {0,1}  (B-operand: col=lane&31, k=16c+8*lhalf+e)
    const float* Xb = X + (size_t)blockIdx.x * BM * DIM;
    const int xrow = w * 32 + lrow;
    const float4* xp = (const float4*)(Xb + xrow * DIM);
    f16x8 xfr[4];
    float nxa = 0.f;                       // approximate ||x||^2 (filter-delta only)
#pragma unroll
    for (int c = 0; c < 4; ++c) {
        const float4 a0 = xp[4 * c + 2 * lhalf + 0];
        const float4 a1 = xp[4 * c + 2 * lhalf + 1];
        nxa = fmaf(a0.x, a0.x, nxa); nxa = fmaf(a0.y, a0.y, nxa);
        nxa = fmaf(a0.z, a0.z, nxa); nxa = fmaf(a0.w, a0.w, nxa);
        nxa = fmaf(a1.x, a1.x, nxa); nxa = fmaf(a1.y, a1.y, nxa);
        nxa = fmaf(a1.z, a1.z, nxa); nxa = fmaf(a1.w, a1.w, nxa);
        f16x8 v;
        v[0] = (_Float16)a0.x; v[1] = (_Float16)a0.y; v[2] = (_Float16)a0.z; v[3] = (_Float16)a0.w;
        v[4] = (_Float16)a1.x; v[5] = (_Float16)a1.y; v[6] = (_Float16)a1.z; v[7] = (_Float16)a1.w;
        xfr[c] = v;
    }
    nxa += __shfl_xor(nxa, 32, 64);        // lane-pair holds complementary k halves

    // per-lane scalar trackers (v = cm - 2*dot; nx cancels in m2-m1); st = step id
    float m1 = __builtin_inff(), m2 = __builtin_inff();
    int st = 0;

    const f16x8* Eg = (const f16x8*)Ebf;
#pragma unroll 2
    for (int T = 0; T < 16; ++T) {
        // A-frags (32 codes) from global: imm-offset dwordx4, L1/L2-hot
        const f16x8 b0 = Eg[T * 256 + (0 + lhalf) * 32 + lrow];
        const f16x8 b1 = Eg[T * 256 + (2 + lhalf) * 32 + lrow];
        const f16x8 b2 = Eg[T * 256 + (4 + lhalf) * 32 + lrow];
        const f16x8 b3 = Eg[T * 256 + (6 + lhalf) * 32 + lrow];
        // cm for this lane's 16 slots (codes 32T + 4*lhalf + {0..3,8..11,16..19,24..27})
        const float4 cm0 = *(const float4*)(cvec + 32 * T + 0 + 4 * lhalf);
        const float4 cm1 = *(const float4*)(cvec + 32 * T + 8 + 4 * lhalf);
        const float4 cm2 = *(const float4*)(cvec + 32 * T + 16 + 4 * lhalf);
        const float4 cm3 = *(const float4*)(cvec + 32 * T + 24 + 4 * lhalf);

        f32x16 acc;
#pragma unroll
        for (int s = 0; s < 16; ++s) acc[s] = 0.f;
        acc = __builtin_amdgcn_mfma_f32_32x32x16_f16(b0, xfr[0], acc, 0, 0, 0);
        acc = __builtin_amdgcn_mfma_f32_32x32x16_f16(b1, xfr[1], acc, 0, 0, 0);
        acc = __builtin_amdgcn_mfma_f32_32x32x16_f16(b2, xfr[2], acc, 0, 0, 0);
        acc = __builtin_amdgcn_mfma_f32_32x32x16_f16(b3, xfr[3], acc, 0, 0, 0);

#pragma unroll
        for (int s = 0; s < 16; ++s) {      // codes ascend with s within lane ✓
            const float cm = (s < 4) ? COMP(cm0, s & 3) : (s < 8) ? COMP(cm1, s & 3)
                           : (s < 12) ? COMP(cm2, s & 3) : COMP(cm3, s & 3);
            const float v = fmaf(-2.f, acc[s], cm);
            m2 = fminf(fmaxf(m1, v), m2);          // new second-min
            const bool b = v < m1;                 // strict < : first-min wins
            st = b ? (T * 16 + s) : st;
            m1 = b ? v : m1;
        }
    }
    // reconstruct code from step id (monotone in code order within lane)
    int i1 = 32 * (st >> 4) + 4 * lhalf + ((st & 15) & 3) + 8 * ((st & 15) >> 2);

    // ---- merge lane <-> lane+32 (disjoint code subsets of the same row)
    {
        const float od = __shfl_xor(m1, 32, 64);
        const int oi = __shfl_xor(i1, 32, 64);
        const float os = __shfl_xor(m2, 32, 64);
        m2 = fminf(fminf(m2, os), fmaxf(m1, od));
        const bool tk = od < m1 || (od == m1 && oi < i1);
        m1 = tk ? od : m1; i1 = tk ? oi : i1;
    }

    // ---- ambiguity test + commit (lanes 0..31 hold rows w*32+lane)
    {
        const float semax = *semaxp;
        const float KA = 0.00256f * semax + 6.3e-7f;
        const float KB = 4.5e-7f;     // covers fp32 combine-order rounding (~3 ulp of nx)
        const float delta = fmaf(sqrtf(nxa), KA, nxa * KB);
        if (lhalf == 0) {
            if (m2 - m1 > delta) {          // provably unique fp32 winner
                bidxs[xrow] = i1;
                atomicAdd(&hist[i1], 1u);
            } else {                        // ambiguous: exact fp32 rescan
                rlist[atomicAdd(&rcount, 1)] = xrow;
            }
        }
    }
    __syncthreads();

    // ---- rescue: exact fp32 rescan (identical arithmetic to the passing fp32 kernel)
    for (int q = w; q < rcount; q += TPB / 64) {
        const int row = rlist[q];
        const float4* xr4 = (const float4*)(Xb + row * DIM);
        float4 xg[16];
#pragma unroll
        for (int g = 0; g < 16; ++g) xg[g] = xr4[g];
        // exact ||x||^2, numpy pairwise 8-acc order
        float r[8];
#pragma unroll
        for (int j = 0; j < 8; ++j) { const float t = COMP(xg[j >> 2], j & 3); r[j] = t * t; }
#pragma unroll
        for (int i = 1; i < 8; ++i)
#pragma unroll
            for (int j = 0; j < 8; ++j) {
                const int k = 8 * i + j;
                const float t = COMP(xg[k >> 2], k & 3);
                r[j] = fmaf(t, t, r[j]);
            }
        const float nxr = ((r[0] + r[1]) + (r[2] + r[3])) + ((r[4] + r[5]) + (r[6] + r[7]));
        float bmv = __builtin_inff(); int bix = 0;
#pragma unroll 1
        for (int t = 0; t < 8; ++t) {
            const int cde = l + 64 * t;
            const float4* ep = (const float4*)(E + (size_t)cde * DIM);
            float dacc = 0.f;
#pragma unroll
            for (int g = 0; g < 16; ++g) {   // sequential k: exact reference order
                const float4 ev = ep[g];
                dacc = fmaf(xg[g].x, ev.x, dacc);
                dacc = fmaf(xg[g].y, ev.y, dacc);
                dacc = fmaf(xg[g].z, ev.z, dacc);
                dacc = fmaf(xg[g].w, ev.w, dacc);
            }
            const float d2 = fmaf(-2.f, dacc, nxr) + cvec[cde];
            if (d2 < bmv) { bmv = d2; bix = cde; }
        }
#pragma unroll
        for (int off = 1; off < 64; off <<= 1) {
            const float od = __shfl_xor(bmv, off, 64);
            const int oi = __shfl_xor(bix, off, 64);
            if (od < bmv || (od == bmv && oi < bix)) { bmv = od; bix = oi; }
        }
        if (l == 0) { bidxs[row] = bix; atomicAdd(&hist[bix], 1u); }
    }
    __syncthreads();

    // ---- epilogue: quantised_st + loss (x re-read coalesced, L3-hot; E L2-hot)
    float* outb = out + (size_t)blockIdx.x * BM * DIM;
    float ls = 0.f;
#pragma unroll
    for (int i = 0; i < 8; ++i) {
        const int gi = i * TPB + tid;
        const int row = gi >> 4;
        const int colL = gi & 15;
        const int bq = bidxs[row];
        const float4 qv = ((const float4*)E)[bq * 16 + colL];
        const float4 xv = ((const float4*)Xb)[gi];
        float4 o;
        { const float t = qv.x - xv.x; o.x = xv.x + t; const float dd = xv.x - qv.x; ls = fmaf(dd, dd, ls); }
        { const float t = qv.y - xv.y; o.y = xv.y + t; const float dd = xv.y - qv.y; ls = fmaf(dd, dd, ls); }
        { const float t = qv.z - xv.z; o.z = xv.z + t; const float dd = xv.z - qv.z; ls = fmaf(dd, dd, ls); }
        { const float t = qv.w - xv.w; o.w = xv.w + t; const float dd = xv.w - qv.w; ls = fmaf(dd, dd, ls); }
        ((float4*)outb)[gi] = o;
    }

#pragma unroll
    for (int off = 32; off > 0; off >>= 1) ls += __shfl_down(ls, off);
    if (l == 0) red[w] = (double)ls;
    __syncthreads();
    if (tid == 0) {
        double s = 0.0;
#pragma unroll
        for (int wv = 0; wv < TPB / 64; ++wv) s += red[wv];
        atomicAdd(lsum, s);    // 1024 total double atomics: negligible
    }

    // ---- histogram flush: per-block slab (no atomics) or fallback atomic path
    if (slab) {
        unsigned int* sb = slab + (size_t)blockIdx.x * MCODE;
        for (int i = tid; i < MCODE; i += TPB) sb[i] = hist[i];
    } else {
        for (int i = tid; i < MCODE; i += TPB) {
            const unsigned int v = hist[i];
            if (v) atomicAdd(&counts[i], v);
        }
    }
}

// ---------------- mid reduce: 1024 slabs -> 32 partials (no atomics)
__global__ __launch_bounds__(512) void vq_mid(const unsigned int* __restrict__ slab,
                                              unsigned int* __restrict__ mid) {
    const int t = threadIdx.x, b = blockIdx.x;
    unsigned int s = 0;
#pragma unroll 4
    for (int j = 0; j < 32; ++j) s += slab[(size_t)(b * 32 + j) * MCODE + t];
    mid[b * MCODE + t] = s;
}

// ---------------- finalize: losses + perplexity (cnt = nsl stacked 512-bin arrays)
__global__ __launch_bounds__(512) void vq_fin(const unsigned int* __restrict__ cnt,
                                              int nsl,
                                              const double* __restrict__ lsum,
                                              float* __restrict__ out3) {
    __shared__ double sred[8];
    const int t = threadIdx.x;
    unsigned int c = 0;
    for (int b = 0; b < nsl; ++b) c += cnt[b * MCODE + t];
    const double avg = (double)c / (double)ROWS;
    double term = avg * log(avg + 1e-10);
#pragma unroll
    for (int off = 32; off > 0; off >>= 1) term += __shfl_down(term, off);
    const int lane = t & 63, wid = t >> 6;
    if (lane == 0) sred[wid] = term;
    __syncthreads();
    if (t == 0) {
        double s = 0.0;
#pragma unroll
        for (int w = 0; w < 8; ++w) s += sred[w];
        const float perp = (float)exp(-s);
        const float rl = (float)(*lsum / (double)QELEMS);
        out3[0] = 0.25f * rl;   // commitment_loss
        out3[1] = rl;           // codebook_loss
        out3[2] = perp;         // perplexity
    }
}

extern "C" void kernel_launch(void* const* d_in, const int* in_sizes, int n_in,
                              void* d_out, int out_size, void* d_ws, size_t ws_size,
                              hipStream_t stream) {
    const float* X = (const float*)d_in[0];       // [32,4096,64] fp32
    const float* E = (const float*)d_in[1];       // [512,64] fp32
    float* out = (float*)d_out;                   // 8388608 + 3 floats

    char* ws = (char*)d_ws;
    double* lsum          = (double*)(ws + 0);                 //    8 B
    unsigned int* counts  = (unsigned int*)(ws + 8);           // 2048 B (fallback)
    float* cvec           = (float*)(ws + 2056);               // 2048 B
    float* semaxp         = (float*)(ws + 4104);               //    4 B (+pad)
    _Float16* Ebf         = (_Float16*)(ws + 4112);            // 65536 B, 16B-aligned
    unsigned int* slab    = (unsigned int*)(ws + 69648);       // 1024*512*4 = 2 MB
    unsigned int* mid     = (unsigned int*)(ws + 69648 + 2097152);  // 64 KB
    const size_t NEED = 69648 + 2097152 + 65536;
    const bool big = ws_size >= NEED;

    vq_prep<<<1, MCODE, 0, stream>>>(E, cvec, semaxp, Ebf, counts, lsum);
    vq_main<<<ROWS / BM, TPB, 0, stream>>>(X, E, cvec, semaxp, Ebf, out, counts, lsum,
                                           big ? slab : (unsigned int*)nullptr);
    if (big) {
        vq_mid<<<32, 512, 0, stream>>>(slab, mid);
        vq_fin<<<1, 512, 0, stream>>>(mid, 32, lsum, out + QELEMS);
    } else {
        vq_fin<<<1, 512, 0, stream>>>(counts, 1, lsum, out + QELEMS);
    }
}

// Round 8
// 102.355 us; speedup vs baseline: 1.7521x; 1.7521x over previous
//
#include <hip/hip_runtime.h>
#include <cmath>

#define DIM    64
#define MCODE  512
#define ROWS   131072
#define QELEMS 8388608   // 32*4096*64
#define BM     128       // rows per block
#define TPB    256

typedef _Float16 f16x8 __attribute__((ext_vector_type(8)));
typedef float    f32x16 __attribute__((ext_vector_type(16)));

#define COMP(v, c) ((c) == 0 ? (v).x : (c) == 1 ? (v).y : (c) == 2 ? (v).z : (v).w)

// ---------------- prep: cvec, error-bound constants, fp16-tiled codebook
__global__ __launch_bounds__(512) void vq_prep(const float* __restrict__ E,
                                               float* __restrict__ cvec,
                                               float* __restrict__ consts,  // [0]=max||ê||, [1]=max||e-ê||
                                               _Float16* __restrict__ Ebf,
                                               unsigned int* __restrict__ counts,
                                               double* __restrict__ lsum) {
    __shared__ float smax[512];
    const int m = threadIdx.x;            // 512 threads, 1 block
    counts[m] = 0u;
    if (m == 0) *lsum = 0.0;
    const float* e = E + (size_t)m * DIM;
    float r[8];
#pragma unroll
    for (int j = 0; j < 8; ++j) r[j] = e[j] * e[j];
#pragma unroll
    for (int i = 1; i < 8; ++i)
#pragma unroll
        for (int j = 0; j < 8; ++j) r[j] += e[8 * i + j] * e[8 * i + j];
    cvec[m] = ((r[0] + r[1]) + (r[2] + r[3])) + ((r[4] + r[5]) + (r[6] + r[7]));

    // fp16 codebook (MFMA-A tiled granule order) + exact conversion-error norms
    // code m: T=m>>5, lrow=m&31; granule g -> index T*256 + g*32 + lrow
    const int T = m >> 5, lrow = m & 31;
    f16x8* dst = (f16x8*)Ebf;
    float en16 = 0.f, err2 = 0.f;
#pragma unroll
    for (int g = 0; g < 8; ++g) {
        f16x8 hv;
#pragma unroll
        for (int j = 0; j < 8; ++j) {
            const float ef = e[8 * g + j];
            const _Float16 h = (_Float16)ef;
            hv[j] = h;
            const float hf = (float)h;
            en16 = fmaf(hf, hf, en16);
            const float d = ef - hf;                 // exact (Sterbenz)
            err2 = fmaf(d, d, err2);
        }
        dst[T * 256 + g * 32 + lrow] = hv;
    }

    smax[m] = en16;
    __syncthreads();
    for (int s = 256; s > 0; s >>= 1) {
        if (m < s) smax[m] = fmaxf(smax[m], smax[m + s]);
        __syncthreads();
    }
    if (m == 0) consts[0] = sqrtf(smax[0]) * 1.0001f;
    __syncthreads();
    smax[m] = err2;
    __syncthreads();
    for (int s = 256; s > 0; s >>= 1) {
        if (m < s) smax[m] = fmaxf(smax[m], smax[m + s]);
        __syncthreads();
    }
    if (m == 0) consts[1] = sqrtf(smax[0]) * 1.0001f;
}

// ---------------- main: f16-MFMA filter (codes=A-rows, x=B-cols) + cooperative exact rescue
__global__ __launch_bounds__(TPB, 4) void vq_main(const float* __restrict__ X,
                                                  const float* __restrict__ E,
                                                  const float* __restrict__ cvec,
                                                  const float* __restrict__ consts,
                                                  const _Float16* __restrict__ Ebf,
                                                  float* __restrict__ out,
                                                  unsigned int* __restrict__ counts,
                                                  double* __restrict__ lsum,
                                                  unsigned int* __restrict__ slab) {
    __shared__ int bidxs[BM];
    __shared__ unsigned int hist[MCODE];   // 2 KB
    __shared__ int rlist[BM];
    __shared__ int rcount;
    __shared__ __align__(16) float4 xrl[16];   // rescue x-row stage
    __shared__ float rbd[TPB / 64];
    __shared__ int rbi[TPB / 64];
    __shared__ double red[TPB / 64];

    const int tid = threadIdx.x;
    const int w = tid >> 6;
    const int l = tid & 63;
    const int lhalf = l >> 5;
    const int lrow = l & 31;

    for (int i = tid; i < MCODE; i += TPB) hist[i] = 0u;
    if (tid == 0) rcount = 0;
    __syncthreads();

    // ---- x fragments straight from global: lane owns row w*32+lrow,
    //      k-granules 4c + 2*lhalf + {0,1}; exact ||x||^2 and ||x-x̂||^2 alongside
    const float* Xb = X + (size_t)blockIdx.x * BM * DIM;
    const int xrow = w * 32 + lrow;
    const float4* xp = (const float4*)(Xb + xrow * DIM);
    f16x8 xfr[4];
    float xn2 = 0.f, dx2 = 0.f;
#pragma unroll
    for (int c = 0; c < 4; ++c) {
        const float4 a0 = xp[4 * c + 2 * lhalf + 0];
        const float4 a1 = xp[4 * c + 2 * lhalf + 1];
        f16x8 v;
        v[0] = (_Float16)a0.x; v[1] = (_Float16)a0.y; v[2] = (_Float16)a0.z; v[3] = (_Float16)a0.w;
        v[4] = (_Float16)a1.x; v[5] = (_Float16)a1.y; v[6] = (_Float16)a1.z; v[7] = (_Float16)a1.w;
        xfr[c] = v;
        float hf, d;
        hf = (float)v[0]; d = a0.x - hf; dx2 = fmaf(d, d, dx2); xn2 = fmaf(a0.x, a0.x, xn2);
        hf = (float)v[1]; d = a0.y - hf; dx2 = fmaf(d, d, dx2); xn2 = fmaf(a0.y, a0.y, xn2);
        hf = (float)v[2]; d = a0.z - hf; dx2 = fmaf(d, d, dx2); xn2 = fmaf(a0.z, a0.z, xn2);
        hf = (float)v[3]; d = a0.w - hf; dx2 = fmaf(d, d, dx2); xn2 = fmaf(a0.w, a0.w, xn2);
        hf = (float)v[4]; d = a1.x - hf; dx2 = fmaf(d, d, dx2); xn2 = fmaf(a1.x, a1.x, xn2);
        hf = (float)v[5]; d = a1.y - hf; dx2 = fmaf(d, d, dx2); xn2 = fmaf(a1.y, a1.y, xn2);
        hf = (float)v[6]; d = a1.z - hf; dx2 = fmaf(d, d, dx2); xn2 = fmaf(a1.z, a1.z, xn2);
        hf = (float)v[7]; d = a1.w - hf; dx2 = fmaf(d, d, dx2); xn2 = fmaf(a1.w, a1.w, xn2);
    }
    xn2 += __shfl_xor(xn2, 32, 64);        // lane pair holds complementary k halves
    dx2 += __shfl_xor(dx2, 32, 64);

    // per-lane scalar trackers (v = cm - 2*dot; nx cancels in m2-m1); st = step id
    float m1 = __builtin_inff(), m2 = __builtin_inff();
    int st = 0;

    const f16x8* Eg = (const f16x8*)Ebf;
#pragma unroll 2
    for (int T = 0; T < 16; ++T) {
        const f16x8 b0 = Eg[T * 256 + (0 + lhalf) * 32 + lrow];
        const f16x8 b1 = Eg[T * 256 + (2 + lhalf) * 32 + lrow];
        const f16x8 b2 = Eg[T * 256 + (4 + lhalf) * 32 + lrow];
        const f16x8 b3 = Eg[T * 256 + (6 + lhalf) * 32 + lrow];
        const float4 cm0 = *(const float4*)(cvec + 32 * T + 0 + 4 * lhalf);
        const float4 cm1 = *(const float4*)(cvec + 32 * T + 8 + 4 * lhalf);
        const float4 cm2 = *(const float4*)(cvec + 32 * T + 16 + 4 * lhalf);
        const float4 cm3 = *(const float4*)(cvec + 32 * T + 24 + 4 * lhalf);

        f32x16 acc;
#pragma unroll
        for (int s = 0; s < 16; ++s) acc[s] = 0.f;
        acc = __builtin_amdgcn_mfma_f32_32x32x16_f16(b0, xfr[0], acc, 0, 0, 0);
        acc = __builtin_amdgcn_mfma_f32_32x32x16_f16(b1, xfr[1], acc, 0, 0, 0);
        acc = __builtin_amdgcn_mfma_f32_32x32x16_f16(b2, xfr[2], acc, 0, 0, 0);
        acc = __builtin_amdgcn_mfma_f32_32x32x16_f16(b3, xfr[3], acc, 0, 0, 0);

#pragma unroll
        for (int s = 0; s < 16; ++s) {      // codes ascend with s within lane
            const float cm = (s < 4) ? COMP(cm0, s & 3) : (s < 8) ? COMP(cm1, s & 3)
                           : (s < 12) ? COMP(cm2, s & 3) : COMP(cm3, s & 3);
            const float v = fmaf(-2.f, acc[s], cm);
            m2 = fminf(fmaxf(m1, v), m2);          // new second-min
            const bool b = v < m1;                 // strict < : first-min wins
            st = b ? (T * 16 + s) : st;
            m1 = b ? v : m1;
        }
    }
    int i1 = 32 * (st >> 4) + 4 * lhalf + ((st & 15) & 3) + 8 * ((st & 15) >> 2);

    // ---- merge lane <-> lane+32 (disjoint code subsets of the same row)
    {
        const float od = __shfl_xor(m1, 32, 64);
        const int oi = __shfl_xor(i1, 32, 64);
        const float os = __shfl_xor(m2, 32, 64);
        m2 = fminf(fminf(m2, os), fmaxf(m1, od));
        const bool tk = od < m1 || (od == m1 && oi < i1);
        m1 = tk ? od : m1; i1 = tk ? oi : i1;
    }

    // ---- tight rigorous ambiguity test + commit
    {
        const float2 cst = *(const float2*)consts;     // x: max||ê||, y: max||e-ê||
        const float dxn = sqrtf(dx2) * 1.02f;
        const float xn  = sqrtf(xn2) * 1.02f;
        // |v16 - (d2_ref - nx)| <= 2(dxn*max||ê|| + xn*max||e-ê||) + combine ulps
        const float delta = 2.1f * fmaf(dxn, cst.x, xn * cst.y) + 3.2e-7f * xn2 + 2e-6f;
        if (lhalf == 0) {
            if (m2 - m1 > delta) {          // provably unique fp32 winner
                bidxs[xrow] = i1;
                atomicAdd(&hist[i1], 1u);
            } else {                        // ambiguous: exact cooperative rescan
                rlist[atomicAdd(&rcount, 1)] = xrow;
            }
        }
    }
    __syncthreads();

    // ---- cooperative rescue: whole block per row, 2 codes/thread, exact fp32
    for (int ri = 0; ri < rcount; ++ri) {
        const int row = rlist[ri];
        if (tid < 16) xrl[tid] = ((const float4*)(Xb + (size_t)row * DIM))[tid];
        __syncthreads();
        // exact ||x||^2, numpy pairwise 8-acc order (broadcast LDS reads)
        const float* xf = (const float*)xrl;
        float r[8];
#pragma unroll
        for (int j = 0; j < 8; ++j) { const float t = xf[j]; r[j] = t * t; }
#pragma unroll
        for (int i = 1; i < 8; ++i)
#pragma unroll
            for (int j = 0; j < 8; ++j) { const float t = xf[8 * i + j]; r[j] = fmaf(t, t, r[j]); }
        const float nxr = ((r[0] + r[1]) + (r[2] + r[3])) + ((r[4] + r[5]) + (r[6] + r[7]));

        float bmv = __builtin_inff(); int bix = 0;
#pragma unroll
        for (int cc = 0; cc < 2; ++cc) {
            const int code = 2 * tid + cc;           // ascending within thread
            const float4* ep = (const float4*)(E + (size_t)code * DIM);
            float dacc = 0.f;
#pragma unroll
            for (int g = 0; g < 16; ++g) {           // sequential k: exact reference order
                const float4 ev = ep[g];
                const float4 xv = xrl[g];
                dacc = fmaf(xv.x, ev.x, dacc);
                dacc = fmaf(xv.y, ev.y, dacc);
                dacc = fmaf(xv.z, ev.z, dacc);
                dacc = fmaf(xv.w, ev.w, dacc);
            }
            const float d2 = fmaf(-2.f, dacc, nxr) + cvec[code];
            if (d2 < bmv) { bmv = d2; bix = code; }
        }
#pragma unroll
        for (int off = 1; off < 64; off <<= 1) {
            const float od = __shfl_xor(bmv, off, 64);
            const int oi = __shfl_xor(bix, off, 64);
            if (od < bmv || (od == bmv && oi < bix)) { bmv = od; bix = oi; }
        }
        if (l == 0) { rbd[w] = bmv; rbi[w] = bix; }
        __syncthreads();
        if (tid == 0) {
            float bb = rbd[0]; int ii = rbi[0];
#pragma unroll
            for (int wv = 1; wv < TPB / 64; ++wv)
                if (rbd[wv] < bb || (rbd[wv] == bb && rbi[wv] < ii)) { bb = rbd[wv]; ii = rbi[wv]; }
            bidxs[row] = ii;
            atomicAdd(&hist[ii], 1u);
        }
        __syncthreads();   // xrl/rbd reused next iteration
    }
    __syncthreads();

    // ---- epilogue: quantised_st + loss (x re-read coalesced, L3-hot; E L2-hot)
    float* outb = out + (size_t)blockIdx.x * BM * DIM;
    float ls = 0.f;
#pragma unroll
    for (int i = 0; i < 8; ++i) {
        const int gi = i * TPB + tid;
        const int row = gi >> 4;
        const int colL = gi & 15;
        const int bq = bidxs[row];
        const float4 qv = ((const float4*)E)[bq * 16 + colL];
        const float4 xv = ((const float4*)Xb)[gi];
        float4 o;
        { const float t = qv.x - xv.x; o.x = xv.x + t; const float dd = xv.x - qv.x; ls = fmaf(dd, dd, ls); }
        { const float t = qv.y - xv.y; o.y = xv.y + t; const float dd = xv.y - qv.y; ls = fmaf(dd, dd, ls); }
        { const float t = qv.z - xv.z; o.z = xv.z + t; const float dd = xv.z - qv.z; ls = fmaf(dd, dd, ls); }
        { const float t = qv.w - xv.w; o.w = xv.w + t; const float dd = xv.w - qv.w; ls = fmaf(dd, dd, ls); }
        ((float4*)outb)[gi] = o;
    }

#pragma unroll
    for (int off = 32; off > 0; off >>= 1) ls += __shfl_down(ls, off);
    if (l == 0) red[w] = (double)ls;
    __syncthreads();
    if (tid == 0) {
        double s = 0.0;
#pragma unroll
        for (int wv = 0; wv < TPB / 64; ++wv) s += red[wv];
        atomicAdd(lsum, s);
    }

    // ---- histogram flush: per-block slab (no atomics) or fallback atomic path
    if (slab) {
        unsigned int* sb = slab + (size_t)blockIdx.x * MCODE;
        for (int i = tid; i < MCODE; i += TPB) sb[i] = hist[i];
    } else {
        for (int i = tid; i < MCODE; i += TPB) {
            const unsigned int v = hist[i];
            if (v) atomicAdd(&counts[i], v);
        }
    }
}

// ---------------- mid reduce: 1024 slabs -> 32 partials (no atomics)
__global__ __launch_bounds__(512) void vq_mid(const unsigned int* __restrict__ slab,
                                              unsigned int* __restrict__ mid) {
    const int t = threadIdx.x, b = blockIdx.x;
    unsigned int s = 0;
#pragma unroll 4
    for (int j = 0; j < 32; ++j) s += slab[(size_t)(b * 32 + j) * MCODE + t];
    mid[b * MCODE + t] = s;
}

// ---------------- finalize: losses + perplexity
__global__ __launch_bounds__(512) void vq_fin(const unsigned int* __restrict__ cnt,
                                              int nsl,
                                              const double* __restrict__ lsum,
                                              float* __restrict__ out3) {
    __shared__ double sred[8];
    const int t = threadIdx.x;
    unsigned int c = 0;
    for (int b = 0; b < nsl; ++b) c += cnt[b * MCODE + t];
    const double avg = (double)c / (double)ROWS;
    double term = avg * log(avg + 1e-10);
#pragma unroll
    for (int off = 32; off > 0; off >>= 1) term += __shfl_down(term, off);
    const int lane = t & 63, wid = t >> 6;
    if (lane == 0) sred[wid] = term;
    __syncthreads();
    if (t == 0) {
        double s = 0.0;
#pragma unroll
        for (int w = 0; w < 8; ++w) s += sred[w];
        const float perp = (float)exp(-s);
        const float rl = (float)(*lsum / (double)QELEMS);
        out3[0] = 0.25f * rl;   // commitment_loss
        out3[1] = rl;           // codebook_loss
        out3[2] = perp;         // perplexity
    }
}

extern "C" void kernel_launch(void* const* d_in, const int* in_sizes, int n_in,
                              void* d_out, int out_size, void* d_ws, size_t ws_size,
                              hipStream_t stream) {
    const float* X = (const float*)d_in[0];       // [32,4096,64] fp32
    const float* E = (const float*)d_in[1];       // [512,64] fp32
    float* out = (float*)d_out;                   // 8388608 + 3 floats

    char* ws = (char*)d_ws;
    double* lsum          = (double*)(ws + 0);                 //    8 B
    unsigned int* counts  = (unsigned int*)(ws + 8);           // 2048 B (fallback)
    float* cvec           = (float*)(ws + 2056);               // 2048 B
    float* consts         = (float*)(ws + 4104);               //    8 B
    _Float16* Ebf         = (_Float16*)(ws + 4112);            // 65536 B, 16B-aligned
    unsigned int* slab    = (unsigned int*)(ws + 69648);       // 2 MB
    unsigned int* mid     = (unsigned int*)(ws + 69648 + 2097152);  // 64 KB
    const size_t NEED = 69648 + 2097152 + 65536;
    const bool big = ws_size >= NEED;

    vq_prep<<<1, MCODE, 0, stream>>>(E, cvec, consts, Ebf, counts, lsum);
    vq_main<<<ROWS / BM, TPB, 0, stream>>>(X, E, cvec, consts, Ebf, out, counts, lsum,
                                           big ? slab : (unsigned int*)nullptr);
    if (big) {
        vq_mid<<<32, 512, 0, stream>>>(slab, mid);
        vq_fin<<<1, 512, 0, stream>>>(mid, 32, lsum, out + QELEMS);
    } else {
        vq_fin<<<1, 512, 0, stream>>>(counts, 1, lsum, out + QELEMS);
    }
}